// Round 8
// baseline (212.804 us; speedup 1.0000x reference)
//
#include <hip/hip_runtime.h>
#include <stdint.h>

#define NH 8
#define NB 8
#define NN 1024
#define ND 128
#define NK 16
#define NF (NB*NN)          // 8192 flat (b,n) rows
#define C2EXP 0.36067376022224085f   // (1/sqrt(16)) * log2(e), folded into Q proj
#define LSTR 136            // LDS row stride (bf16 elems): 272 B = 17*16 B

typedef float f32x16 __attribute__((ext_vector_type(16)));
typedef short bf16x8 __attribute__((ext_vector_type(8)));

__device__ __forceinline__ uint16_t f2bf(float f){
  uint32_t x = __float_as_uint(f);
  uint32_t r = (x + 0x7fffu + ((x>>16)&1u)) >> 16;   // RNE
  return (uint16_t)r;
}
__device__ __forceinline__ float fast_exp2(float x){
#if __has_builtin(__builtin_amdgcn_exp2f)
  return __builtin_amdgcn_exp2f(x);
#else
  return exp2f(x);
#endif
}

struct ProjArgs { const float* x[8]; const float* w[8]; };

// Fused projection + mask-pack. blockIdx.y==0 -> pack role (64 blocks x 128
// rows, dispatched FIRST so its ~8 us of mask reads hide under proj);
// y=1..8 -> projection p=y-1.
//
// MFMA projection: block = 128 rows x one projection p (128 out cols).
// fp32 x,W in; bf16 out. Q/K -> [h][row][k]; V (p=2,5,7) -> VT SUBTILED:
// [hb][tile=n>>5][k(16)][col=n&31], n mu-permuted (mu swaps quartets 1<->2
// within each 16-group -- stays inside a 32-col subtile). Each attention
// n-tile's V is then a contiguous 1 KB block.
// Q projections (p=0,3) pre-scaled by C2EXP so attention exp is raw exp2.
// 512 threads / 8 waves: wave = (rt 0..3 row-group) x (nh2 nt-half).
__global__ __launch_bounds__(512, 4) void proj_kernel(
    ProjArgs args, uint16_t* ws,
    const int* __restrict__ mask, uint32_t* __restrict__ packN,
    uint16_t* __restrict__ onesw)
{
  __shared__ __align__(16) uint16_t WT[128*LSTR];  // [n=h*16+k][d]
  __shared__ __align__(16) uint16_t S[128*LSTR];   // epilogue staging
  const int rb = blockIdx.x;           // row-block of 128
  const int tid = threadIdx.x;
  const int wave = tid >> 6, lane = tid & 63;

  const int p = (int)blockIdx.y - 1;
  if (p < 0) {
    // ---- pack role: packN[row][t] bit j = mask[row][t*32+j]; ones region.
    if (rb == 0) {
      for (int i = tid; i < 16384; i += 512) onesw[i] = 0x3F80;  // 1.0bf
    }
    const int rbase = rb*128 + wave*16;
    for (int rr = 0; rr < 16; ++rr) {
      const int row = rbase + rr;
      const int* mp = mask + (size_t)row*NN;
      uint32_t* dst = packN + (size_t)row*32;
      for (int wq = 0; wq < 16; ++wq) {
        int v = mp[wq*64 + lane];
        unsigned long long bal = __ballot(v != 0);
        if (lane == 0) { dst[wq*2] = (uint32_t)bal; dst[wq*2+1] = (uint32_t)(bal>>32); }
      }
    }
    return;
  }

  const float4* w4 = (const float4*)args.w[p];     // [h][d][k] fp32
  #pragma unroll
  for (int i = 0; i < 8; ++i) {
    int e4 = i*512 + tid;              // coalesced float4 (4096 total)
    float4 f = w4[e4];
    int e = e4*4;
    int h = e >> 11, d = (e >> 4) & 127, k = e & 15;   // k in {0,4,8,12}
    uint16_t* wr = &WT[(h*16 + k)*LSTR + d];
    wr[0*LSTR] = f2bf(f.x); wr[1*LSTR] = f2bf(f.y);
    wr[2*LSTR] = f2bf(f.z); wr[3*LSTR] = f2bf(f.w);
  }
  __syncthreads();

  const int l5 = lane >> 5, lm = lane & 31;
  const int rt = wave & 3, nh2 = wave >> 2;
  const int r0 = rb*128 + rt*32;
  const float* xrow = args.x[p] + (size_t)(r0 + lm)*ND + l5*8;

  bf16x8 afr[8];
  #pragma unroll
  for (int kt = 0; kt < 8; ++kt) {
    float4 f0 = *(const float4*)(xrow + kt*16);
    float4 f1 = *(const float4*)(xrow + kt*16 + 4);
    bf16x8 a;
    a[0]=f2bf(f0.x); a[1]=f2bf(f0.y); a[2]=f2bf(f0.z); a[3]=f2bf(f0.w);
    a[4]=f2bf(f1.x); a[5]=f2bf(f1.y); a[6]=f2bf(f1.z); a[7]=f2bf(f1.w);
    afr[kt] = a;
  }

  const bool tr = (p==2)|(p==5)|(p==7);
  const float qsc = (p==0 || p==3) ? C2EXP : 1.0f;
  #pragma unroll
  for (int nt2 = 0; nt2 < 2; ++nt2) {
    const int nt = nh2*2 + nt2;
    f32x16 acc;
    #pragma unroll
    for (int i = 0; i < 16; ++i) acc[i] = 0.f;
    #pragma unroll
    for (int kt = 0; kt < 8; ++kt) {
      bf16x8 b = *(const bf16x8*)(&WT[(nt*32 + lm)*LSTR + kt*16 + l5*8]);
      acc = __builtin_amdgcn_mfma_f32_32x32x16_bf16(afr[kt], b, acc, 0, 0, 0);
    }
    #pragma unroll
    for (int i = 0; i < 16; ++i) {
      int r = rt*32 + (i&3) + 8*(i>>2) + 4*l5;     // local row 0..127
      int c = nt*32 + lm;
      if (tr) {
        int t2 = (r>>2)&3;                         // mu permutation on n
        int rp = (t2==1 || t2==2) ? (r^12) : r;
        S[c*LSTR + rp] = f2bf(acc[i]);
      } else {
        S[r*LSTR + c] = f2bf(acc[i]*qsc);
      }
    }
  }
  __syncthreads();

  uint16_t* dst = ws + (size_t)p*((size_t)NH*NF*NK);
  if (!tr) {
    #pragma unroll
    for (int it = 0; it < 4; ++it) {
      int c = it*512 + tid;            // 2048 chunks of 8 elems
      int row = c >> 4, cg = c & 15;
      bf16x8 v = *(const bf16x8*)(&S[row*LSTR + cg*8]);
      int h = cg >> 1, k8 = cg & 1;
      *(bf16x8*)(dst + ((size_t)h*NF + rb*128 + row)*NK + k8*8) = v;
    }
  } else {
    const int b = rb >> 3, nb = (rb & 7)*128;
    #pragma unroll
    for (int it = 0; it < 4; ++it) {
      int c = it*512 + tid;
      int col = c >> 4, ng = c & 15;   // col = h*16+k
      bf16x8 v = *(const bf16x8*)(&S[col*LSTR + ng*8]);
      int h = col >> 4, k = col & 15;
      int pn = nb + ng*8;              // global (mu'd) n position, 8-aligned
      // subtiled: [hb][tile=pn>>5][k][col=pn&31]
      *(bf16x8*)(dst + (size_t)(h*NB + b)*16384
                     + (size_t)(pn >> 5)*512 + k*32 + (pn & 31)) = v;
    }
  }
}

// One attention stream over this wave's 16 n-tiles (n-half nh).
// S^T form: lane = query col. No max subtraction. O^T = V^T(A) x P^T(B);
// V^T mu-permuted in n so packed exp dwords ARE the B-fragment.
// v6: K direct from XCD-resident L2 (no LDS, no barriers), subtiled VT
// (per-tile V contiguous 1 KB -> ~8 lines/tile), V + K prefetched one
// tile ahead (registers only; single St accumulator -- v5's spill lesson).
// vl: per-lane V subtile ptr (lane 16 -> ones region => L in O[reg 8]).
template<bool MASKED>
__device__ __forceinline__ void attn_stream(
    const uint16_t* __restrict__ kp, bf16x8 aq,
    const uint16_t* __restrict__ vb, const uint4* __restrict__ pmw4,
    int nh, int l5, int lm, f32x16& O)
{
  f32x16 Z;
  #pragma unroll
  for (int i = 0; i < 16; ++i) Z[i] = 0.f;

  const int base_n = nh*512;
  const bool vload = (lm < 17);
  const uint16_t* kl = kp + (size_t)(base_n + lm)*NK + l5*8;
  const uint16_t* vl = vb + (size_t)nh*8192 + l5*8;   // subtile stride 512

  uint4 mq, mqn;
  if (MASKED) { mq = pmw4[nh*4]; mqn = mq; }

  bf16x8 av1, av2, av1n, av2n;
  #pragma unroll
  for (int i = 0; i < 8; ++i) { av1[i]=0; av2[i]=0; av1n[i]=0; av2n[i]=0; }

  bf16x8 kf_c = *(const bf16x8*)(kl);        // K fragment for tile 0
  bf16x8 kf_n;
  if (vload) {                               // V for tile 0
    av1 = *(const bf16x8*)(vl);
    av2 = *(const bf16x8*)(vl + 16);
  }

  #pragma unroll
  for (int t = 0; t < 16; ++t) {
    if (t < 15) {
      if (vload) {                           // V for tile t+1: issue early
        const uint16_t* vp = vl + (t+1)*512;
        av1n = *(const bf16x8*)(vp);
        av2n = *(const bf16x8*)(vp + 16);
      }
      kf_n = *(const bf16x8*)(kl + (t+1)*512);   // K[t+1]
    }
    if (MASKED && (t&3)==0 && t < 12) mqn = pmw4[nh*4 + (t>>2) + 1];

    f32x16 St = __builtin_amdgcn_mfma_f32_32x32x16_bf16(kf_c, aq, Z, 0, 0, 0);

    uint32_t mws = 0u;
    if (MASKED) {
      uint32_t w = ((t&3)==0) ? mq.x : ((t&3)==1) ? mq.y
                 : ((t&3)==2) ? mq.z : mq.w;
      mws = w >> (4*l5);
    }
    // pairwise exp2 -> truncate-pack; via mu-permuted V^T these dwords
    // ARE the PV B-fragment. Live p-state stays ~4 floats.
    union { uint32_t u[4]; bf16x8 v; } B1, B2;
    #pragma unroll
    for (int k = 0; k < 4; ++k) {
      float p0 = fast_exp2(St[2*k]);
      float p1 = fast_exp2(St[2*k+1]);
      float p8 = fast_exp2(St[2*k+8]);
      float p9 = fast_exp2(St[2*k+9]);
      if (MASKED) {
        const int i0 = 2*k, i1 = 2*k+1, i8 = 2*k+8, i9 = 2*k+9;
        if ((mws >> ((i0&3) + 8*(i0>>2))) & 1u) p0 = 0.f;
        if ((mws >> ((i1&3) + 8*(i1>>2))) & 1u) p1 = 0.f;
        if ((mws >> ((i8&3) + 8*(i8>>2))) & 1u) p8 = 0.f;
        if ((mws >> ((i9&3) + 8*(i9>>2))) & 1u) p9 = 0.f;
      }
      B1.u[k] = __builtin_amdgcn_perm(__float_as_uint(p1),
                                      __float_as_uint(p0), 0x07060302u);
      B2.u[k] = __builtin_amdgcn_perm(__float_as_uint(p9),
                                      __float_as_uint(p8), 0x07060302u);
    }
    O = __builtin_amdgcn_mfma_f32_32x32x16_bf16(av1, B1.v, O, 0, 0, 0);
    O = __builtin_amdgcn_mfma_f32_32x32x16_bf16(av2, B2.v, O, 0, 0, 0);

    if (t < 15) { kf_c = kf_n; av1 = av1n; av2 = av2n; }
    if (MASKED && (t&3)==3) mq = mqn;
  }
}

// Fused attention, ONE stream per block (load-balanced):
//   z=0: node nn (masked), out -> hnn ; z=1: node nc -> hnc ; z=2: color -> hc.
// Streams have independent softmaxes; node heads = hnn + hnc is summed in
// outproj (out-projection is linear). 3072 uniform blocks of 256 threads
// (4 waves = qt(2) x nh(2), 64 q-rows each).
// XCD-aware decode: blockIdx.x = h*8 + b, so lin%8 = b keeps each XCD's
// K/V/Q/packN slice (~2.2 MB) resident in its private L2.
// No K LDS staging (direct L2 reads); LDS = 4.6 KB combine buffer only;
// launch_bounds(256,5) -> 5 blocks/CU (20 waves/CU), reg budget 102.
__global__ __launch_bounds__(256, 5) void attn_kernel(
    const uint16_t* __restrict__ Qn_, const uint16_t* __restrict__ Knn,
    const uint16_t* __restrict__ VTnn, const uint16_t* __restrict__ Knc,
    const uint16_t* __restrict__ VTnc,
    const uint16_t* __restrict__ Qc_, const uint16_t* __restrict__ Kn,
    const uint16_t* __restrict__ VTn,
    const uint32_t* __restrict__ packN, const uint16_t* __restrict__ onesb,
    uint16_t* __restrict__ hnn_, uint16_t* __restrict__ hnc_,
    uint16_t* __restrict__ hc_)
{
  __shared__ float cw[1152];                 // 4*32*9 floats = 4.6 KB
  const int z = blockIdx.z;
  const uint16_t* Q  = (z == 2) ? Qc_ : Qn_;
  const uint16_t* K  = (z == 0) ? Knn : (z == 1) ? Knc : Kn;
  const uint16_t* VT = (z == 0) ? VTnn : (z == 1) ? VTnc : VTn;
  uint16_t* outp     = (z == 0) ? hnn_ : (z == 1) ? hnc_ : hc_;

  const int h = blockIdx.x >> 3, b = blockIdx.x & 7;   // XCD = b
  const int hb = h*8 + b;
  const size_t base = ((size_t)h*NF + (size_t)b*NN)*NK;
  const int tid = threadIdx.x;

  const int wave = tid >> 6, lane = tid & 63;
  const int l5 = lane >> 5, lm = lane & 31;
  const int qt = wave & 1, nh = wave >> 1;
  const int q = blockIdx.y*64 + qt*32 + lm;

  const bf16x8 aq = *(const bf16x8*)(Q + base + (size_t)q*NK + l5*8);
  const uint4* pmw4 = (const uint4*)(packN + ((size_t)b*NN + q)*32);

  // subtiled VT: lane lm<16 owns row lm (32 elems) of each 1 KB subtile;
  // lane 16 reads the ones region with the same uniform stride.
  const uint16_t* VTb = VT + (size_t)hb*(NK*NN);
  const uint16_t* vb = (lm < 16) ? (VTb + (size_t)lm*32) : onesb;

  f32x16 O;
  #pragma unroll
  for (int i = 0; i < 16; ++i) O[i] = 0.f;

  if (z == 0) attn_stream<true >(K + base, aq, vb, pmw4,   nh, l5, lm, O);
  else        attn_stream<false>(K + base, aq, vb, nullptr, nh, l5, lm, O);

  // L = O[reg 8] (row v=16, ones): l5=0 lanes hold it, l5=1 hold 0
  float L1 = O[8] + __shfl_xor(O[8], 32, 64);

  // stride 9 floats (36 B): lanes 0..31 map to distinct banks (gcd(9,32)=1)
  float* cwp = cw + (size_t)((qt*2 + l5)*32 + lm)*9;
  if (nh == 1) {
    #pragma unroll
    for (int i = 0; i < 8; ++i) cwp[i] = O[i];
    cwp[8] = L1;
  }
  __syncthreads();
  if (nh == 0) {
    const float l1 = L1 + cwp[8];
    const float i1 = (l1 > 0.f) ? 1.f/l1 : 0.f;
    uint32_t w[4];
    #pragma unroll
    for (int k = 0; k < 4; ++k) {
      float va = (O[2*k]   + cwp[2*k])  *i1;
      float vb2 = (O[2*k+1] + cwp[2*k+1])*i1;
      w[k] = ((uint32_t)f2bf(vb2) << 16) | f2bf(va);
    }
    uint16_t* hp = outp + ((size_t)b*NN + q)*128 + h*16 + l5*4;
    *(uint2*)(hp)     = make_uint2(w[0], w[1]);   // v = l5*4 .. +3
    *(uint2*)(hp + 8) = make_uint2(w[2], w[3]);   // v = 8+l5*4 .. +3
  }
}

// MFMA out-projection: out[row][e] = sum_c heads[row][c] * Wout[c][e]; fp32 out.
// v7: 32 rows/block, 256 threads / 4 waves (wave = nt 0..3), grid (256,2).
// WT = 34.8 KB -> 4 blocks/CU, 16 waves/CU (2x the old 64-row layout's 8)
// and 512 blocks (2 rounds of residency) for a latency-bound kernel.
// s=0 (node): heads = hnn + hnc, realized as two MFMA accumulate chains
// (out-projection is linear; MFMA pipe is idle here anyway).
__global__ __launch_bounds__(256, 4) void outproj_kernel(
    const uint16_t* __restrict__ hnn, const uint16_t* __restrict__ hnc,
    const uint16_t* __restrict__ hc,
    const float* __restrict__ wn, const float* __restrict__ wc,
    float* __restrict__ out)
{
  __shared__ __align__(16) uint16_t WT[128*LSTR];  // [e][c]
  const int s = blockIdx.y;            // 0 node, 1 color
  const int rb = blockIdx.x;           // 256 blocks of 32 rows
  const int tid = threadIdx.x;
  const float* wsrc = s ? wc : wn;     // [c=h*16+v][e] row-major 128x128
  const float4* w4 = (const float4*)wsrc;
  #pragma unroll
  for (int i = 0; i < 16; ++i) {
    int e4 = i*256 + tid;              // 4096 float4s
    float4 f = w4[e4];
    int e = e4*4;
    int c = e >> 7, col = e & 127;     // 4 consecutive cols, same c
    uint16_t* wr = &WT[col*LSTR + c];
    wr[0*LSTR] = f2bf(f.x); wr[1*LSTR] = f2bf(f.y);
    wr[2*LSTR] = f2bf(f.z); wr[3*LSTR] = f2bf(f.w);
  }
  __syncthreads();

  const int wave = tid >> 6, lane = tid & 63;
  const int l5 = lane >> 5, lm = lane & 31;
  const int nt = wave;                 // 0..3
  const int r0 = rb*32;
  const size_t hoff = (size_t)(r0 + lm)*128 + l5*8;
  const uint16_t* hp1 = (s ? hc : hnn) + hoff;
  bf16x8 afr[8], afr2[8];
  #pragma unroll
  for (int kt = 0; kt < 8; ++kt) afr[kt] = *(const bf16x8*)(hp1 + kt*16);
  if (!s) {
    const uint16_t* hp2 = hnc + hoff;
    #pragma unroll
    for (int kt = 0; kt < 8; ++kt) afr2[kt] = *(const bf16x8*)(hp2 + kt*16);
  }

  float* dst = out + (size_t)s*((size_t)NF*ND) + (size_t)r0*ND;
  f32x16 acc;
  #pragma unroll
  for (int i = 0; i < 16; ++i) acc[i] = 0.f;
  #pragma unroll
  for (int kt = 0; kt < 8; ++kt) {
    bf16x8 b = *(const bf16x8*)(&WT[(nt*32 + lm)*LSTR + kt*16 + l5*8]);
    acc = __builtin_amdgcn_mfma_f32_32x32x16_bf16(afr[kt], b, acc, 0, 0, 0);
    if (!s) acc = __builtin_amdgcn_mfma_f32_32x32x16_bf16(afr2[kt], b, acc, 0, 0, 0);
  }
  #pragma unroll
  for (int i = 0; i < 16; ++i) {
    int r = (i&3) + 8*(i>>2) + 4*l5;
    dst[(size_t)r*ND + nt*32 + lm] = acc[i];
  }
}

extern "C" void kernel_launch(void* const* d_in, const int* in_sizes, int n_in,
                              void* d_out, int out_size, void* d_ws, size_t ws_size,
                              hipStream_t stream)
{
  const float* q_n = (const float*)d_in[0];
  const float* q_c = (const float*)d_in[1];
  const int* mask = (const int*)d_in[2];
  const float* W[10];
  for (int i = 0; i < 10; ++i) W[i] = (const float*)d_in[3+i];
  // W[0]=W_query_n W[1]=W_key_nn W[2]=W_val_nn W[3]=W_key_c W[4]=W_val_c
  // W[5]=W_query_c W[6]=W_key_n  W[7]=W_val_n  W[8]=W_out_node W[9]=W_out_color

  uint16_t* ws16 = (uint16_t*)d_ws;
  const size_t PE = (size_t)NH*NF*NK;   // 1,048,576 elements per slot
  uint16_t* Qc   = ws16 + 0*PE;
  uint16_t* Kn   = ws16 + 1*PE;
  uint16_t* VTn  = ws16 + 2*PE;   // [hb][tile][16][32], n mu-permuted
  uint16_t* Qn   = ws16 + 3*PE;
  uint16_t* Knn  = ws16 + 4*PE;
  uint16_t* VTnn = ws16 + 5*PE;
  uint16_t* Knc  = ws16 + 6*PE;
  uint16_t* VTnc = ws16 + 7*PE;
  uint16_t* hnn  = ws16 + 8*PE;         // node-nn heads [row][h*16+v] bf16
  uint32_t* packN   = (uint32_t*)(ws16 + 9*PE);   // 1 MB (512K u16 elems)
  uint16_t* onesb   = ws16 + 9*PE + 524288;       // upper half of packN slot
  uint16_t* hc   = ws16 + 10*PE;        // color heads
  uint16_t* hnc  = ws16 + 11*PE;        // node-nc heads

  ProjArgs pa;
  pa.x[0]=q_c; pa.w[0]=W[5];  // Q_c (pre-scaled C2EXP)
  pa.x[1]=q_n; pa.w[1]=W[6];  // K_n
  pa.x[2]=q_n; pa.w[2]=W[7];  // V_n  (subtiled, mu-permuted)
  pa.x[3]=q_n; pa.w[3]=W[0];  // Q_n (pre-scaled C2EXP)
  pa.x[4]=q_n; pa.w[4]=W[1];  // K_nn
  pa.x[5]=q_n; pa.w[5]=W[2];  // V_nn (subtiled, mu-permuted)
  pa.x[6]=q_c; pa.w[6]=W[3];  // K_nc
  pa.x[7]=q_c; pa.w[7]=W[4];  // V_nc (subtiled, mu-permuted)
  // y==0: pack role (dispatched first, hides under proj); y=1..8: p=y-1
  proj_kernel<<<dim3(64, 9), 512, 0, stream>>>(pa, ws16, mask, packN, onesb);

  attn_kernel<<<dim3(64, 16, 3), 256, 0, stream>>>(
      Qn, Knn, VTnn, Knc, VTnc, Qc, Kn, VTn, packN, onesb,
      hnn, hnc, hc);

  outproj_kernel<<<dim3(256, 2), 256, 0, stream>>>(hnn, hnc, hc,
                                                   W[8], W[9], (float*)d_out);
}

// Round 9
// 161.942 us; speedup vs baseline: 1.3141x; 1.3141x over previous
//
#include <hip/hip_runtime.h>
#include <stdint.h>

#define NH 8
#define NB 8
#define NN 1024
#define ND 128
#define NK 16
#define NF (NB*NN)          // 8192 flat (b,n) rows
#define C2EXP 0.36067376022224085f   // (1/sqrt(16)) * log2(e), folded into Q proj
#define LSTR 136            // LDS row stride (bf16 elems): 272 B = 17*16 B

typedef float f32x16 __attribute__((ext_vector_type(16)));
typedef short bf16x8 __attribute__((ext_vector_type(8)));

__device__ __forceinline__ uint16_t f2bf(float f){
  uint32_t x = __float_as_uint(f);
  uint32_t r = (x + 0x7fffu + ((x>>16)&1u)) >> 16;   // RNE
  return (uint16_t)r;
}
__device__ __forceinline__ float fast_exp2(float x){
#if __has_builtin(__builtin_amdgcn_exp2f)
  return __builtin_amdgcn_exp2f(x);
#else
  return exp2f(x);
#endif
}

// pack mask n-major: packN[row=b*NN+q][t] bit j = mask[b][q][t*32+j].
// Also writes a 16384-elem bf16 ones region (V^T lane-16 row; sized so the
// uniform subtile stride nh*8192 + t*512 stays in-bounds for both n-halves).
// Fine-grained (2048 blocks x 4 rows): R8 showed coarse fusion (128 rows /
// block) serializes 256 load+ballot steps per wave and stalls the grid.
__global__ __launch_bounds__(256) void pack_kernel(const int* __restrict__ mask,
                                                   uint32_t* __restrict__ packN,
                                                   uint16_t* __restrict__ onesw){
  if (blockIdx.x == 0) {
    for (int i = threadIdx.x; i < 16384; i += 256) onesw[i] = 0x3F80;  // 1.0bf
  }
  const int w = threadIdx.x >> 6, lane = threadIdx.x & 63;
  const int row = blockIdx.x*4 + w;          // 0..8191
  const int* mp = mask + (size_t)row*NN;
  uint32_t* dst = packN + (size_t)row*32;
  for (int wq = 0; wq < 16; ++wq) {
    int v = mp[wq*64 + lane];
    unsigned long long bal = __ballot(v != 0);
    if (lane == 0) { dst[wq*2] = (uint32_t)bal; dst[wq*2+1] = (uint32_t)(bal>>32); }
  }
}

struct ProjArgs { const float* x[8]; const float* w[8]; };

// MFMA projection: block = 128 rows x one projection p (128 out cols).
// fp32 x,W in; bf16 out. Q/K -> [h][row][k]; V (p=2,5,7) -> VT SUBTILED:
// [hb][tile=n>>5][k(16)][col=n&31], n mu-permuted (mu swaps quartets 1<->2
// within each 16-group -- stays inside a 32-col subtile). Each attention
// n-tile's V is then a contiguous 1 KB block.
// Q projections (p=0,3) pre-scaled by C2EXP so attention exp is raw exp2.
// 512 threads / 8 waves: wave = (rt 0..3 row-group) x (nh2 nt-half).
__global__ __launch_bounds__(512, 4) void proj_kernel(ProjArgs args, uint16_t* ws){
  __shared__ __align__(16) uint16_t WT[128*LSTR];  // [n=h*16+k][d]
  __shared__ __align__(16) uint16_t S[128*LSTR];   // epilogue staging
  const int p = blockIdx.y;
  const int rb = blockIdx.x;           // row-block of 128
  const int tid = threadIdx.x;

  const float4* w4 = (const float4*)args.w[p];     // [h][d][k] fp32
  #pragma unroll
  for (int i = 0; i < 8; ++i) {
    int e4 = i*512 + tid;              // coalesced float4 (4096 total)
    float4 f = w4[e4];
    int e = e4*4;
    int h = e >> 11, d = (e >> 4) & 127, k = e & 15;   // k in {0,4,8,12}
    uint16_t* wr = &WT[(h*16 + k)*LSTR + d];
    wr[0*LSTR] = f2bf(f.x); wr[1*LSTR] = f2bf(f.y);
    wr[2*LSTR] = f2bf(f.z); wr[3*LSTR] = f2bf(f.w);
  }
  __syncthreads();

  const int wave = tid >> 6, lane = tid & 63;
  const int l5 = lane >> 5, lm = lane & 31;
  const int rt = wave & 3, nh2 = wave >> 2;
  const int r0 = rb*128 + rt*32;
  const float* xrow = args.x[p] + (size_t)(r0 + lm)*ND + l5*8;

  bf16x8 afr[8];
  #pragma unroll
  for (int kt = 0; kt < 8; ++kt) {
    float4 f0 = *(const float4*)(xrow + kt*16);
    float4 f1 = *(const float4*)(xrow + kt*16 + 4);
    bf16x8 a;
    a[0]=f2bf(f0.x); a[1]=f2bf(f0.y); a[2]=f2bf(f0.z); a[3]=f2bf(f0.w);
    a[4]=f2bf(f1.x); a[5]=f2bf(f1.y); a[6]=f2bf(f1.z); a[7]=f2bf(f1.w);
    afr[kt] = a;
  }

  const bool tr = (p==2)|(p==5)|(p==7);
  const float qsc = (p==0 || p==3) ? C2EXP : 1.0f;
  #pragma unroll
  for (int nt2 = 0; nt2 < 2; ++nt2) {
    const int nt = nh2*2 + nt2;
    f32x16 acc;
    #pragma unroll
    for (int i = 0; i < 16; ++i) acc[i] = 0.f;
    #pragma unroll
    for (int kt = 0; kt < 8; ++kt) {
      bf16x8 b = *(const bf16x8*)(&WT[(nt*32 + lm)*LSTR + kt*16 + l5*8]);
      acc = __builtin_amdgcn_mfma_f32_32x32x16_bf16(afr[kt], b, acc, 0, 0, 0);
    }
    #pragma unroll
    for (int i = 0; i < 16; ++i) {
      int r = rt*32 + (i&3) + 8*(i>>2) + 4*l5;     // local row 0..127
      int c = nt*32 + lm;
      if (tr) {
        int t2 = (r>>2)&3;                         // mu permutation on n
        int rp = (t2==1 || t2==2) ? (r^12) : r;
        S[c*LSTR + rp] = f2bf(acc[i]);
      } else {
        S[r*LSTR + c] = f2bf(acc[i]*qsc);
      }
    }
  }
  __syncthreads();

  uint16_t* dst = ws + (size_t)p*((size_t)NH*NF*NK);
  if (!tr) {
    #pragma unroll
    for (int it = 0; it < 4; ++it) {
      int c = it*512 + tid;            // 2048 chunks of 8 elems
      int row = c >> 4, cg = c & 15;
      bf16x8 v = *(const bf16x8*)(&S[row*LSTR + cg*8]);
      int h = cg >> 1, k8 = cg & 1;
      *(bf16x8*)(dst + ((size_t)h*NF + rb*128 + row)*NK + k8*8) = v;
    }
  } else {
    const int b = rb >> 3, nb = (rb & 7)*128;
    #pragma unroll
    for (int it = 0; it < 4; ++it) {
      int c = it*512 + tid;
      int col = c >> 4, ng = c & 15;   // col = h*16+k
      bf16x8 v = *(const bf16x8*)(&S[col*LSTR + ng*8]);
      int h = col >> 4, k = col & 15;
      int pn = nb + ng*8;              // global (mu'd) n position, 8-aligned
      // subtiled: [hb][tile=pn>>5][k][col=pn&31]
      *(bf16x8*)(dst + (size_t)(h*NB + b)*16384
                     + (size_t)(pn >> 5)*512 + k*32 + (pn & 31)) = v;
    }
  }
}

// One attention stream over this wave's 16 n-tiles (n-half nh).
// S^T form: lane = query col. No max subtraction. O^T = V^T(A) x P^T(B);
// V^T mu-permuted in n so packed exp dwords ARE the B-fragment.
// v6: K direct from XCD-resident L2 (no LDS, no barriers), subtiled VT
// (per-tile V contiguous 1 KB -> ~8 lines/tile), V + K prefetched one
// tile ahead (registers only; single St accumulator -- v5's spill lesson).
// vl: per-lane V subtile ptr (lane 16 -> ones region => L in O[reg 8]).
template<bool MASKED>
__device__ __forceinline__ void attn_stream(
    const uint16_t* __restrict__ kp, bf16x8 aq,
    const uint16_t* __restrict__ vb, const uint4* __restrict__ pmw4,
    int nh, int l5, int lm, f32x16& O)
{
  f32x16 Z;
  #pragma unroll
  for (int i = 0; i < 16; ++i) Z[i] = 0.f;

  const int base_n = nh*512;
  const bool vload = (lm < 17);
  const uint16_t* kl = kp + (size_t)(base_n + lm)*NK + l5*8;
  const uint16_t* vl = vb + (size_t)nh*8192 + l5*8;   // subtile stride 512

  uint4 mq, mqn;
  if (MASKED) { mq = pmw4[nh*4]; mqn = mq; }

  bf16x8 av1, av2, av1n, av2n;
  #pragma unroll
  for (int i = 0; i < 8; ++i) { av1[i]=0; av2[i]=0; av1n[i]=0; av2n[i]=0; }

  bf16x8 kf_c = *(const bf16x8*)(kl);        // K fragment for tile 0
  bf16x8 kf_n;
  if (vload) {                               // V for tile 0
    av1 = *(const bf16x8*)(vl);
    av2 = *(const bf16x8*)(vl + 16);
  }

  #pragma unroll
  for (int t = 0; t < 16; ++t) {
    if (t < 15) {
      if (vload) {                           // V for tile t+1: issue early
        const uint16_t* vp = vl + (t+1)*512;
        av1n = *(const bf16x8*)(vp);
        av2n = *(const bf16x8*)(vp + 16);
      }
      kf_n = *(const bf16x8*)(kl + (t+1)*512);   // K[t+1]
    }
    if (MASKED && (t&3)==0 && t < 12) mqn = pmw4[nh*4 + (t>>2) + 1];

    f32x16 St = __builtin_amdgcn_mfma_f32_32x32x16_bf16(kf_c, aq, Z, 0, 0, 0);

    uint32_t mws = 0u;
    if (MASKED) {
      uint32_t w = ((t&3)==0) ? mq.x : ((t&3)==1) ? mq.y
                 : ((t&3)==2) ? mq.z : mq.w;
      mws = w >> (4*l5);
    }
    // pairwise exp2 -> truncate-pack; via mu-permuted V^T these dwords
    // ARE the PV B-fragment. Live p-state stays ~4 floats.
    union { uint32_t u[4]; bf16x8 v; } B1, B2;
    #pragma unroll
    for (int k = 0; k < 4; ++k) {
      float p0 = fast_exp2(St[2*k]);
      float p1 = fast_exp2(St[2*k+1]);
      float p8 = fast_exp2(St[2*k+8]);
      float p9 = fast_exp2(St[2*k+9]);
      if (MASKED) {
        const int i0 = 2*k, i1 = 2*k+1, i8 = 2*k+8, i9 = 2*k+9;
        if ((mws >> ((i0&3) + 8*(i0>>2))) & 1u) p0 = 0.f;
        if ((mws >> ((i1&3) + 8*(i1>>2))) & 1u) p1 = 0.f;
        if ((mws >> ((i8&3) + 8*(i8>>2))) & 1u) p8 = 0.f;
        if ((mws >> ((i9&3) + 8*(i9>>2))) & 1u) p9 = 0.f;
      }
      B1.u[k] = __builtin_amdgcn_perm(__float_as_uint(p1),
                                      __float_as_uint(p0), 0x07060302u);
      B2.u[k] = __builtin_amdgcn_perm(__float_as_uint(p9),
                                      __float_as_uint(p8), 0x07060302u);
    }
    O = __builtin_amdgcn_mfma_f32_32x32x16_bf16(av1, B1.v, O, 0, 0, 0);
    O = __builtin_amdgcn_mfma_f32_32x32x16_bf16(av2, B2.v, O, 0, 0, 0);

    if (t < 15) { kf_c = kf_n; av1 = av1n; av2 = av2n; }
    if (MASKED && (t&3)==3) mq = mqn;
  }
}

// Fused attention, ONE stream per block (load-balanced):
//   z=0: node nn (masked), out -> hnn ; z=1: node nc -> hnc ; z=2: color -> hc.
// Streams have independent softmaxes; node heads = hnn + hnc is summed in
// outproj (out-projection is linear). 3072 uniform blocks of 256 threads
// (4 waves = qt(2) x nh(2), 64 q-rows each).
// XCD-aware decode: blockIdx.x = h*8 + b, so lin%8 = b keeps each XCD's
// K/V/Q/packN slice (~2.2 MB) resident in its private L2.
// No K LDS staging (direct L2 reads); LDS = 4.6 KB combine buffer only;
// launch_bounds(256,5) -> 5 blocks/CU (20 waves/CU), reg budget 102.
__global__ __launch_bounds__(256, 5) void attn_kernel(
    const uint16_t* __restrict__ Qn_, const uint16_t* __restrict__ Knn,
    const uint16_t* __restrict__ VTnn, const uint16_t* __restrict__ Knc,
    const uint16_t* __restrict__ VTnc,
    const uint16_t* __restrict__ Qc_, const uint16_t* __restrict__ Kn,
    const uint16_t* __restrict__ VTn,
    const uint32_t* __restrict__ packN, const uint16_t* __restrict__ onesb,
    uint16_t* __restrict__ hnn_, uint16_t* __restrict__ hnc_,
    uint16_t* __restrict__ hc_)
{
  __shared__ float cw[1152];                 // 4*32*9 floats = 4.6 KB
  const int z = blockIdx.z;
  const uint16_t* Q  = (z == 2) ? Qc_ : Qn_;
  const uint16_t* K  = (z == 0) ? Knn : (z == 1) ? Knc : Kn;
  const uint16_t* VT = (z == 0) ? VTnn : (z == 1) ? VTnc : VTn;
  uint16_t* outp     = (z == 0) ? hnn_ : (z == 1) ? hnc_ : hc_;

  const int h = blockIdx.x >> 3, b = blockIdx.x & 7;   // XCD = b
  const int hb = h*8 + b;
  const size_t base = ((size_t)h*NF + (size_t)b*NN)*NK;
  const int tid = threadIdx.x;

  const int wave = tid >> 6, lane = tid & 63;
  const int l5 = lane >> 5, lm = lane & 31;
  const int qt = wave & 1, nh = wave >> 1;
  const int q = blockIdx.y*64 + qt*32 + lm;

  const bf16x8 aq = *(const bf16x8*)(Q + base + (size_t)q*NK + l5*8);
  const uint4* pmw4 = (const uint4*)(packN + ((size_t)b*NN + q)*32);

  // subtiled VT: lane lm<16 owns row lm (32 elems) of each 1 KB subtile;
  // lane 16 reads the ones region with the same uniform stride.
  const uint16_t* VTb = VT + (size_t)hb*(NK*NN);
  const uint16_t* vb = (lm < 16) ? (VTb + (size_t)lm*32) : onesb;

  f32x16 O;
  #pragma unroll
  for (int i = 0; i < 16; ++i) O[i] = 0.f;

  if (z == 0) attn_stream<true >(K + base, aq, vb, pmw4,   nh, l5, lm, O);
  else        attn_stream<false>(K + base, aq, vb, nullptr, nh, l5, lm, O);

  // L = O[reg 8] (row v=16, ones): l5=0 lanes hold it, l5=1 hold 0
  float L1 = O[8] + __shfl_xor(O[8], 32, 64);

  // stride 9 floats (36 B): lanes 0..31 map to distinct banks (gcd(9,32)=1)
  float* cwp = cw + (size_t)((qt*2 + l5)*32 + lm)*9;
  if (nh == 1) {
    #pragma unroll
    for (int i = 0; i < 8; ++i) cwp[i] = O[i];
    cwp[8] = L1;
  }
  __syncthreads();
  if (nh == 0) {
    const float l1 = L1 + cwp[8];
    const float i1 = (l1 > 0.f) ? 1.f/l1 : 0.f;
    uint32_t w[4];
    #pragma unroll
    for (int k = 0; k < 4; ++k) {
      float va = (O[2*k]   + cwp[2*k])  *i1;
      float vb2 = (O[2*k+1] + cwp[2*k+1])*i1;
      w[k] = ((uint32_t)f2bf(vb2) << 16) | f2bf(va);
    }
    uint16_t* hp = outp + ((size_t)b*NN + q)*128 + h*16 + l5*4;
    *(uint2*)(hp)     = make_uint2(w[0], w[1]);   // v = l5*4 .. +3
    *(uint2*)(hp + 8) = make_uint2(w[2], w[3]);   // v = 8+l5*4 .. +3
  }
}

// MFMA out-projection: out[row][e] = sum_c heads[row][c] * Wout[c][e]; fp32 out.
// 32 rows/block, 256 threads / 4 waves (wave = nt 0..3), grid (256,2).
// WT = 34.8 KB -> 4 blocks/CU, 16 waves/CU and 512 blocks (2 residency
// rounds) for a latency-bound kernel.
// s=0 (node): heads = hnn + hnc, realized as two MFMA accumulate chains
// (out-projection is linear; MFMA pipe is idle here anyway).
__global__ __launch_bounds__(256, 4) void outproj_kernel(
    const uint16_t* __restrict__ hnn, const uint16_t* __restrict__ hnc,
    const uint16_t* __restrict__ hc,
    const float* __restrict__ wn, const float* __restrict__ wc,
    float* __restrict__ out)
{
  __shared__ __align__(16) uint16_t WT[128*LSTR];  // [e][c]
  const int s = blockIdx.y;            // 0 node, 1 color
  const int rb = blockIdx.x;           // 256 blocks of 32 rows
  const int tid = threadIdx.x;
  const float* wsrc = s ? wc : wn;     // [c=h*16+v][e] row-major 128x128
  const float4* w4 = (const float4*)wsrc;
  #pragma unroll
  for (int i = 0; i < 16; ++i) {
    int e4 = i*256 + tid;              // 4096 float4s
    float4 f = w4[e4];
    int e = e4*4;
    int c = e >> 7, col = e & 127;     // 4 consecutive cols, same c
    uint16_t* wr = &WT[col*LSTR + c];
    wr[0*LSTR] = f2bf(f.x); wr[1*LSTR] = f2bf(f.y);
    wr[2*LSTR] = f2bf(f.z); wr[3*LSTR] = f2bf(f.w);
  }
  __syncthreads();

  const int wave = tid >> 6, lane = tid & 63;
  const int l5 = lane >> 5, lm = lane & 31;
  const int nt = wave;                 // 0..3
  const int r0 = rb*32;
  const size_t hoff = (size_t)(r0 + lm)*128 + l5*8;
  const uint16_t* hp1 = (s ? hc : hnn) + hoff;
  bf16x8 afr[8], afr2[8];
  #pragma unroll
  for (int kt = 0; kt < 8; ++kt) afr[kt] = *(const bf16x8*)(hp1 + kt*16);
  if (!s) {
    const uint16_t* hp2 = hnc + hoff;
    #pragma unroll
    for (int kt = 0; kt < 8; ++kt) afr2[kt] = *(const bf16x8*)(hp2 + kt*16);
  }

  float* dst = out + (size_t)s*((size_t)NF*ND) + (size_t)r0*ND;
  f32x16 acc;
  #pragma unroll
  for (int i = 0; i < 16; ++i) acc[i] = 0.f;
  #pragma unroll
  for (int kt = 0; kt < 8; ++kt) {
    bf16x8 b = *(const bf16x8*)(&WT[(nt*32 + lm)*LSTR + kt*16 + l5*8]);
    acc = __builtin_amdgcn_mfma_f32_32x32x16_bf16(afr[kt], b, acc, 0, 0, 0);
    if (!s) acc = __builtin_amdgcn_mfma_f32_32x32x16_bf16(afr2[kt], b, acc, 0, 0, 0);
  }
  #pragma unroll
  for (int i = 0; i < 16; ++i) {
    int r = (i&3) + 8*(i>>2) + 4*l5;
    dst[(size_t)r*ND + nt*32 + lm] = acc[i];
  }
}

extern "C" void kernel_launch(void* const* d_in, const int* in_sizes, int n_in,
                              void* d_out, int out_size, void* d_ws, size_t ws_size,
                              hipStream_t stream)
{
  const float* q_n = (const float*)d_in[0];
  const float* q_c = (const float*)d_in[1];
  const int* mask = (const int*)d_in[2];
  const float* W[10];
  for (int i = 0; i < 10; ++i) W[i] = (const float*)d_in[3+i];
  // W[0]=W_query_n W[1]=W_key_nn W[2]=W_val_nn W[3]=W_key_c W[4]=W_val_c
  // W[5]=W_query_c W[6]=W_key_n  W[7]=W_val_n  W[8]=W_out_node W[9]=W_out_color

  uint16_t* ws16 = (uint16_t*)d_ws;
  const size_t PE = (size_t)NH*NF*NK;   // 1,048,576 elements per slot
  uint16_t* Qc   = ws16 + 0*PE;
  uint16_t* Kn   = ws16 + 1*PE;
  uint16_t* VTn  = ws16 + 2*PE;   // [hb][tile][16][32], n mu-permuted
  uint16_t* Qn   = ws16 + 3*PE;
  uint16_t* Knn  = ws16 + 4*PE;
  uint16_t* VTnn = ws16 + 5*PE;
  uint16_t* Knc  = ws16 + 6*PE;
  uint16_t* VTnc = ws16 + 7*PE;
  uint16_t* hnn  = ws16 + 8*PE;         // node-nn heads [row][h*16+v] bf16
  uint32_t* packN   = (uint32_t*)(ws16 + 9*PE);   // 1 MB (512K u16 elems)
  uint16_t* onesb   = ws16 + 9*PE + 524288;       // upper half of packN slot
  uint16_t* hc   = ws16 + 10*PE;        // color heads
  uint16_t* hnc  = ws16 + 11*PE;        // node-nc heads

  pack_kernel<<<2048, 256, 0, stream>>>(mask, packN, onesb);

  ProjArgs pa;
  pa.x[0]=q_c; pa.w[0]=W[5];  // Q_c (pre-scaled C2EXP)
  pa.x[1]=q_n; pa.w[1]=W[6];  // K_n
  pa.x[2]=q_n; pa.w[2]=W[7];  // V_n  (subtiled, mu-permuted)
  pa.x[3]=q_n; pa.w[3]=W[0];  // Q_n (pre-scaled C2EXP)
  pa.x[4]=q_n; pa.w[4]=W[1];  // K_nn
  pa.x[5]=q_n; pa.w[5]=W[2];  // V_nn (subtiled, mu-permuted)
  pa.x[6]=q_c; pa.w[6]=W[3];  // K_nc
  pa.x[7]=q_c; pa.w[7]=W[4];  // V_nc (subtiled, mu-permuted)
  proj_kernel<<<dim3(64, 8), 512, 0, stream>>>(pa, ws16);

  attn_kernel<<<dim3(64, 16, 3), 256, 0, stream>>>(
      Qn, Knn, VTnn, Knc, VTnc, Qc, Kn, VTn, packN, onesb,
      hnn, hnc, hc);

  outproj_kernel<<<dim3(256, 2), 256, 0, stream>>>(hnn, hnc, hc,
                                                   W[8], W[9], (float*)d_out);
}